// Round 11
// baseline (419.085 us; speedup 1.0000x reference)
//
#include <hip/hip_runtime.h>
#include <hip/hip_bf16.h>
#include <stdint.h>

#define B_  4
#define S_  2048
#define D_  1024
#define H_  16
#define DK_ 64
#define M_  (B_*S_)                 // 8192
#define MD_ ((size_t)M_*D_)         // 8388608

typedef unsigned short u16;
typedef unsigned int   u32;
using bh8 = __attribute__((ext_vector_type(8))) short;
using fx4 = __attribute__((ext_vector_type(4))) float;
using us4 = __attribute__((ext_vector_type(4))) unsigned short;

#define C1_ 0.18033688011112042f    // (1/sqrt(64)) * log2(e)

__device__ __forceinline__ u16 f2bf(float f){
  union { float f; u32 u; } v; v.f = f;
  u32 r = v.u + 0x7FFFu + ((v.u >> 16) & 1u);
  return (u16)(r >> 16);
}
__device__ __forceinline__ u16 f2bf_fast(float f){
  union { float f; u32 u; } v; v.f = f;
  return (u16)((v.u + 0x8000u) >> 16);
}
__device__ __forceinline__ float fexp2(float x){
  float r;
  asm("v_exp_f32 %0, %1\n\ts_nop 0" : "=v"(r) : "v"(x));
  return r;
}
// async global->LDS, 16B/lane; LDS dest = wave-uniform base + lane*16
__device__ __forceinline__ void gl16(const void* g, void* l){
  __builtin_amdgcn_global_load_lds(
      (const __attribute__((address_space(1))) unsigned int*)g,
      (__attribute__((address_space(3))) unsigned int*)l, 16, 0, 0);
}

// ---------- fused prep: fp32->bf16 cvt (q,k,v) + 4x W transpose ----------
__global__ __launch_bounds__(256) void prep_k(const float* __restrict__ q,
                                              const float* __restrict__ k,
                                              const float* __restrict__ v,
                                              const float* __restrict__ W0,
                                              const float* __restrict__ W1,
                                              const float* __restrict__ W2,
                                              const float* __restrict__ W3,
                                              u16* __restrict__ dq,
                                              u16* __restrict__ dk,
                                              u16* __restrict__ dv,
                                              u16* __restrict__ WT){
  int id = blockIdx.x;
  int tid = threadIdx.x;
  if (id < 12288){
    int z = id >> 12;
    int i = (id & 4095)*256 + tid;            // n8 = 4096*256 exactly
    const float* in = (z==0)? q : (z==1)? k : v;
    u16* out = (z==0)? dq : (z==1)? dk : dv;
    const float4* p = (const float4*)(in + (size_t)i*8);
    float4 a0 = p[0], a1 = p[1];
    u16 o[8];
    o[0]=f2bf(a0.x); o[1]=f2bf(a0.y); o[2]=f2bf(a0.z); o[3]=f2bf(a0.w);
    o[4]=f2bf(a1.x); o[5]=f2bf(a1.y); o[6]=f2bf(a1.z); o[7]=f2bf(a1.w);
    *(bh8*)(out + (size_t)i*8) = *(bh8*)o;
  } else {
    int id2 = id - 12288;
    int z = id2 >> 10, b2 = id2 & 1023;
    int bx = b2 & 31, by = b2 >> 5;
    const float* in = (z==0)? W0 : (z==1)? W1 : (z==2)? W2 : W3;
    float scale = (z==0)? C1_ : 1.0f;
    u16* o = WT + (size_t)z*1024*1024;
    __shared__ u16 tile[32][33];
    int tx = tid & 31, ty = tid >> 5;         // 32 x 8
    int x0 = bx*32, y0 = by*32;
    #pragma unroll
    for (int j=0;j<32;j+=8) tile[ty+j][tx] = f2bf(in[(size_t)(y0+ty+j)*D_ + x0+tx]*scale);
    __syncthreads();
    #pragma unroll
    for (int j=0;j<32;j+=8) o[(size_t)(x0+ty+j)*D_ + y0+tx] = tile[tx][ty+j];
  }
}

// ---------- unified 8-wave GEMM: 128(M) x 256(N) tile, BK=64 ----------
// (R6-verified, unchanged)
template<int MODE>
__global__ __launch_bounds__(512) void gemm8(const u16* __restrict__ Aqk,
                                             const u16* __restrict__ Av,
                                             const u16* __restrict__ WTb,
                                             u16* __restrict__ Cqk,
                                             u16* __restrict__ VtOut,
                                             float* __restrict__ Cf){
  __shared__ __align__(16) u16 AL[2][128*64];   // 2 x 16 KB
  __shared__ __align__(16) u16 BL[2][256*64];   // 2 x 32 KB

  int hbid = blockIdx.x;
  int xcd = hbid & 7, slot = hbid >> 3;
  int pg  = xcd * (MODE==0 ? 24 : 8) + (slot >> 2);
  int x   = slot & 3;
  int y   = (MODE==0) ? (pg & 63) : pg;
  int z   = (MODE==0) ? (pg >> 6) : 0;

  const u16* A  = (MODE==0 && z==2) ? Av : (Aqk + (size_t)z*MD_);
  const u16* BT = WTb + (size_t)z*1024*1024;
  int tid = threadIdx.x;
  int w = tid >> 6, lane = tid & 63, quad = lane >> 4, ln = lane & 15;
  int wm = w >> 2, wn = w & 3;
  int rowBase = y*128, colBase = x*256;

  auto sA = [&](int buf, int kt, int c){      // c in {0,1}
    int s = c*512 + tid;
    int row = s >> 3, kc = (s & 7) ^ (row & 7);
    gl16(&A[(size_t)(rowBase + row)*D_ + kt*64 + kc*8], &AL[buf][s*8]);
  };
  auto sB = [&](int buf, int kt, int c){      // c in {0..3}
    int s = c*512 + tid;
    int row = s >> 3, kc = (s & 7) ^ (row & 7);
    gl16(&BT[(size_t)(colBase + row)*D_ + kt*64 + kc*8], &BL[buf][s*8]);
  };
  auto ridx = [&](int row, int kc){ return row*64 + ((kc ^ (row & 7))*8); };

  fx4 acc[4][4];
  #pragma unroll
  for (int i=0;i<4;i++)
    #pragma unroll
    for (int j=0;j<4;j++) acc[i][j] = (fx4){0.f,0.f,0.f,0.f};

  sA(0,0,0); sA(0,0,1); sB(0,0,0); sB(0,0,1); sB(0,0,2); sB(0,0,3);
  sB(1,1,0); sB(1,1,1); sB(1,1,2);
  asm volatile("s_waitcnt vmcnt(3)" ::: "memory");
  __builtin_amdgcn_s_barrier();

  for (int it = 0; it < 8; ++it){
    int t = 2*it;
    bool h2 = (t+2 < 16), h3 = (t+3 < 16);
    #pragma unroll
    for (int half = 0; half < 2; ++half){     // buf == half (t even)
      const u16* Ab = &AL[half][0];
      const u16* Bb = &BL[half][0];

      // ---- q0 phase ----
      bh8 bfr[4][2], af0[2][2], af1[2][2];
      #pragma unroll
      for (int n=0;n<4;n++)
        #pragma unroll
        for (int ks=0;ks<2;ks++)
          bfr[n][ks] = *(const bh8*)(&Bb[ridx(wn*64 + n*16 + ln, ks*4+quad)]);
      #pragma unroll
      for (int mi=0;mi<2;mi++)
        #pragma unroll
        for (int ks=0;ks<2;ks++)
          af0[mi][ks] = *(const bh8*)(&Ab[ridx(wm*64 + mi*16 + ln, ks*4+quad)]);
      #pragma unroll
      for (int mi=0;mi<2;mi++)
        #pragma unroll
        for (int ks=0;ks<2;ks++)
          af1[mi][ks] = *(const bh8*)(&Ab[ridx(wm*64 + 32 + mi*16 + ln, ks*4+quad)]);

      if (half == 0){
        sB(1, t+1, 3); sA(1, t+1, 0); sA(1, t+1, 1);
      } else if (h2){
        sB(0, t+2, 3); sA(0, t+2, 0); sA(0, t+2, 1);
      }
      __builtin_amdgcn_s_barrier();
      asm volatile("s_waitcnt lgkmcnt(4)" ::: "memory");   // bfr+af0 done
      __builtin_amdgcn_s_setprio(1);
      #pragma unroll
      for (int mi=0;mi<2;mi++)
        #pragma unroll
        for (int n=0;n<4;n++)
          #pragma unroll
          for (int ks=0;ks<2;ks++)
            acc[mi][n] = __builtin_amdgcn_mfma_f32_16x16x32_bf16(
                            af0[mi][ks], bfr[n][ks], acc[mi][n], 0,0,0);
      __builtin_amdgcn_s_setprio(0);
      __builtin_amdgcn_s_barrier();

      // ---- q1 phase ----
      if (half == 0){
        if (h2){ sB(0, t+2, 0); sB(0, t+2, 1); sB(0, t+2, 2); }
        if (h2) asm volatile("s_waitcnt vmcnt(3)" ::: "memory");
        else    asm volatile("s_waitcnt vmcnt(0)" ::: "memory");
      } else {
        if (h3){ sB(1, t+3, 0); sB(1, t+3, 1); sB(1, t+3, 2); }
        if (h3) asm volatile("s_waitcnt vmcnt(3)" ::: "memory");
        else    asm volatile("s_waitcnt vmcnt(0)" ::: "memory");
      }
      __builtin_amdgcn_s_barrier();
      asm volatile("s_waitcnt lgkmcnt(0)" ::: "memory");   // af1 done
      __builtin_amdgcn_s_setprio(1);
      #pragma unroll
      for (int mi=0;mi<2;mi++)
        #pragma unroll
        for (int n=0;n<4;n++)
          #pragma unroll
          for (int ks=0;ks<2;ks++)
            acc[2+mi][n] = __builtin_amdgcn_mfma_f32_16x16x32_bf16(
                              af1[mi][ks], bfr[n][ks], acc[2+mi][n], 0,0,0);
      __builtin_amdgcn_s_setprio(0);
      __builtin_amdgcn_s_barrier();
    }
  }

  #pragma unroll
  for (int m=0;m<4;m++){
    int row0 = rowBase + wm*64 + m*16 + quad*4;
    #pragma unroll
    for (int n=0;n<4;n++){
      int col = colBase + wn*64 + n*16 + ln;
      if (MODE == 1){
        #pragma unroll
        for (int r=0;r<4;r++)
          Cf[(size_t)(row0 + r)*D_ + col] = acc[m][n][r];
      } else if (z == 2){
        int bb = row0 >> 11, tok = row0 & (S_-1);
        int hh = col >> 6,  vd  = col & 63;
        us4 pk;
        #pragma unroll
        for (int r=0;r<4;r++) pk[r] = f2bf(acc[m][n][r]);
        *(us4*)&VtOut[((size_t)((bb*16+hh)*64+vd))*S_ + tok] = pk;
      } else {
        #pragma unroll
        for (int r=0;r<4;r++)
          (Cqk + (size_t)z*MD_)[(size_t)(row0 + r)*D_ + col] = f2bf(acc[m][n][r]);
      }
    }
  }
}

// ---------- flash attention, causal: uniform-makespan + V-direct ----------
// R10 structure (paired 64-row q-tiles, 33 K-tiles per block, zero skew) +
// V READ DIRECT FROM GLOBAL (Common-mistake #7 / m169): V^T per (b,h) is
// 256 KB and all 16 p-blocks of one bh land on the SAME XCD (id = bh+64p,
// id%8 = bh%8) -> VtG is L2-local; LDS-staging it was pure overhead. The 8
// vf fragments (16B/lane, ln-group lanes share one 64B segment) are loaded
// at tile start and consumed in PV ~280 cyc later (> ~200 cyc L2 latency).
// LDS 40 -> 24 KB: 6 blocks/CU; occupancy cap 50% -> ~62% (VGPR-bound).
// Staging halves (K only); prefetch/dbuf/softmax sequence unchanged (R8).
__global__ __launch_bounds__(256) void attn_k(const u16* __restrict__ Q,
                                              const u16* __restrict__ Kp,
                                              const u16* __restrict__ VtG,
                                              u16* __restrict__ O){
  __shared__ __align__(16) u16 Kt[2][64*64];    // 2 x 8 KB
  __shared__ __align__(16) u16 Pb[4*16*64];     // 8 KB

  int bh = blockIdx.x; int b = bh>>4, h = bh&15;
  int p  = blockIdx.y;                 // 0..15
  int j1 = 31 - p, j2 = p;             // paired 64-row q-tiles; (j1+1)+(j2+1)=33
  int tid = threadIdx.x;
  int w = tid >> 6, lane = tid & 63, quad = lane >> 4, ln = lane & 15;
  size_t headoff = (size_t)h*DK_;

  // per-segment state
  int q0w;                             // = qt*64 + w*16
  bh8 qf0, qf1;
  float m_i, l_i;
  fx4 oacc[4];

  auto loadQ = [&](int j){
    q0w = j*64 + w*16;
    const u16* qp = Q + (size_t)(b*S_ + q0w + ln)*D_ + headoff + quad*8;
    qf0 = *(const bh8*)qp;
    qf1 = *(const bh8*)(qp + 32);
    m_i = -3e38f; l_i = 0.f;
    #pragma unroll
    for (int r=0;r<4;r++) oacc[r] = (fx4){0.f,0.f,0.f,0.f};
  };

  auto writeO = [&](){
    float linv = 1.0f / l_i;
    float lb[4];
    #pragma unroll
    for (int r=0;r<4;r++) lb[r] = __shfl(linv, quad*4 + r, 64);
    #pragma unroll
    for (int r=0;r<4;r++)
      #pragma unroll
      for (int vt=0; vt<4; vt++){
        float ov = oacc[vt][r] * lb[r];
        O[(size_t)(b*S_ + q0w + quad*4 + r)*D_ + headoff + vt*16 + ln] = f2bf(ov);
      }
  };

  auto stage = [&](int k0, int bi){    // K only (V is read direct)
    #pragma unroll
    for (int i=0;i<2;i++){
      int s = i*256 + tid;
      int n = s >> 3, kc = (s & 7) ^ (n & 7);
      gl16(&Kp[(size_t)(b*S_ + k0 + n)*D_ + headoff + kc*8], &Kt[bi][s*8]);
    }
  };

  u16* Pw = &Pb[w*16*64];
  const int nt = 33;                   // (j1+1)+(j2+1), uniform for all blocks
  auto k0_of = [&](int i){ return (i <= j1) ? i*64 : (i - j1 - 1)*64; };
  const u16* Vbh = VtG + (size_t)bh*64*S_;

  loadQ(j1);                           // heavy segment first
  stage(0, 0);
  __syncthreads();                     // drain prologue staging

  for (int i=0; i<nt; i++){
    int cur = i & 1;
    if (i+1 < nt) stage(k0_of(i+1), cur^1);   // prefetch K (spans boundary)
    const u16* Kc = Kt[cur];
    int k0 = k0_of(i);
    bool diag = (i == j1) || (i == nt-1);     // last tile of each segment

    // V fragments for THIS tile: direct from global (L2-local), issued
    // early so ~280 cyc of QK+softmax+PW hides the load latency
    bh8 vfr[2][4];
    #pragma unroll
    for (int s2=0; s2<2; s2++){
      int c = s2*4 + quad;
      #pragma unroll
      for (int vt=0; vt<4; vt++){
        int vd = vt*16 + ln;
        vfr[s2][vt] = *(const bh8*)&Vbh[(size_t)vd*S_ + k0 + c*8];
      }
    }

    // QK^T swapped: sacc[t] = K_frag[t] x Q_frag -> S^T
    fx4 sacc[4];
    __builtin_amdgcn_s_setprio(1);
    #pragma unroll
    for (int t=0;t<4;t++){
      int n = t*16 + ln;
      bh8 kf0 = *(const bh8*)(&Kc[(n*8 + ( quad    ^ (ln&7)))*8]);
      bh8 kf1 = *(const bh8*)(&Kc[(n*8 + ((4+quad) ^ (ln&7)))*8]);
      fx4 zz = (fx4){0.f,0.f,0.f,0.f};
      zz = __builtin_amdgcn_mfma_f32_16x16x32_bf16(kf0, qf0, zz, 0,0,0);
      zz = __builtin_amdgcn_mfma_f32_16x16x32_bf16(kf1, qf1, zz, 0,0,0);
      sacc[t] = zz;
    }
    __builtin_amdgcn_s_setprio(0);

    int qg = q0w + ln;
    if (diag){
      #pragma unroll
      for (int t=0;t<4;t++)
        #pragma unroll
        for (int r=0;r<4;r++){
          int kg = k0 + t*16 + quad*4 + r;
          sacc[t][r] = (kg <= qg) ? sacc[t][r] : -3e38f;
        }
    }

    // row reduce: in-register tree + 2 shfl
    float tm[4];
    #pragma unroll
    for (int t=0;t<4;t++)
      tm[t] = fmaxf(fmaxf(sacc[t][0], sacc[t][1]), fmaxf(sacc[t][2], sacc[t][3]));
    float mloc = fmaxf(fmaxf(tm[0], tm[1]), fmaxf(tm[2], tm[3]));
    mloc = fmaxf(mloc, __shfl_xor(mloc, 16, 64));
    mloc = fmaxf(mloc, __shfl_xor(mloc, 32, 64));

    // defer-max: rescale only when the tile max grew past THR=8 (log2)
    if (__any(mloc > m_i + 8.0f)){
      float mn = fmaxf(m_i, mloc);
      float alpha = fexp2(m_i - mn);
      m_i = mn;
      l_i *= alpha;
      float al[4];
      #pragma unroll
      for (int r=0;r<4;r++) al[r] = __shfl(alpha, quad*4 + r, 64);
      #pragma unroll
      for (int vt=0;vt<4;vt++)
        #pragma unroll
        for (int r=0;r<4;r++)
          oacc[vt][r] *= al[r];
    }
    float mn = m_i;

    float ts[4];
    #pragma unroll
    for (int t=0;t<4;t++){
      #pragma unroll
      for (int r=0;r<4;r++) sacc[t][r] = fexp2(sacc[t][r] - mn);
      ts[t] = (sacc[t][0] + sacc[t][1]) + (sacc[t][2] + sacc[t][3]);
    }
    float rs = (ts[0] + ts[1]) + (ts[2] + ts[3]);
    rs += __shfl_xor(rs, 16, 64);
    rs += __shfl_xor(rs, 32, 64);
    l_i += rs;

    // P^T -> P: phys halfslot hs = (4t+quad) ^ (ln&14)
    #pragma unroll
    for (int t=0;t<4;t++){
      int hs = (t*4 + quad) ^ (ln & 14);
      us4 pk;
      #pragma unroll
      for (int r=0;r<4;r++) pk[r] = f2bf_fast(sacc[t][r]);
      *(us4*)&Pw[ln*64 + hs*4] = pk;
    }
    asm volatile("s_waitcnt lgkmcnt(0)" ::: "memory");

    // PV: 64 keys in 2 chunks, vdim in 4 subtiles; V from registers
    __builtin_amdgcn_s_setprio(1);
    #pragma unroll
    for (int s2=0; s2<2; s2++){
      int c = s2*4 + quad;
      int pm = c ^ ((ln>>1) & 7);
      bh8 pf = *(const bh8*)(&Pw[ln*64 + pm*8]);
      #pragma unroll
      for (int vt=0; vt<4; vt++)
        oacc[vt] = __builtin_amdgcn_mfma_f32_16x16x32_bf16(pf, vfr[s2][vt], oacc[vt], 0,0,0);
    }
    __builtin_amdgcn_s_setprio(0);
    asm volatile("s_waitcnt lgkmcnt(0)" ::: "memory");  // drain before Pw reuse

    if (i == j1){                       // segment boundary: finish j1, start j2
      writeO();
      loadQ(j2);
    }
    __syncthreads();   // K prefetch arrived; buffers safe
  }

  writeO();                             // finish segment 2
}

extern "C" void kernel_launch(void* const* d_in, const int* in_sizes, int n_in,
                              void* d_out, int out_size, void* d_ws, size_t ws_size,
                              hipStream_t stream){
  const float* q  = (const float*)d_in[0];
  const float* k  = (const float*)d_in[1];
  const float* v  = (const float*)d_in[2];
  const float* Wq = (const float*)d_in[3];
  const float* Wk = (const float*)d_in[4];
  const float* Wv = (const float*)d_in[5];
  const float* Wo = (const float*)d_in[6];
  // d_in[7] = causal mask, statically known -> ignored

  u16* ws  = (u16*)d_ws;
  u16* WT  = ws;                                // 4 x 1M bf16 (Wq*C1, Wk, Wv, Wo)^T
  u16* xa  = WT + (size_t)4*1024*1024;          // q bf16
  u16* xb  = xa + MD_;                          // k bf16 (contiguous after xa)
  u16* Qp  = xb + MD_;                          // Q proj (C1-scaled), later O
  u16* Kp  = Qp + MD_;                          // 8 MB + 4*16 MB = 72 MB ws

  // d_out (2*MD_ u16) doubles as scratch until the final GEMM:
  u16* vb  = (u16*)d_out;                       // v bf16       [0,   MD_)
  u16* VtG = vb + MD_;                          // per-head V^T [MD_, 2*MD_)

  prep_k<<<dim3(16384), 256, 0, stream>>>(q, k, v, Wq, Wk, Wv, Wo, xa, xb, vb, WT);

  gemm8<0><<<dim3(768), 512, 0, stream>>>(xa, vb, WT, Qp, VtG, nullptr);      // Qp, Kp, VtG

  attn_k<<<dim3(B_*H_, 16), 256, 0, stream>>>(Qp, Kp, VtG, Qp);               // O over Q

  gemm8<1><<<dim3(256), 512, 0, stream>>>(Qp, nullptr, WT + (size_t)3*1024*1024,
                                          nullptr, nullptr, (float*)d_out);
}

// Round 12
// 318.915 us; speedup vs baseline: 1.3141x; 1.3141x over previous
//
#include <hip/hip_runtime.h>
#include <hip/hip_bf16.h>
#include <stdint.h>

#define B_  4
#define S_  2048
#define D_  1024
#define H_  16
#define DK_ 64
#define M_  (B_*S_)                 // 8192
#define MD_ ((size_t)M_*D_)         // 8388608

typedef unsigned short u16;
typedef unsigned int   u32;
using bh8 = __attribute__((ext_vector_type(8))) short;
using fx4 = __attribute__((ext_vector_type(4))) float;
using us4 = __attribute__((ext_vector_type(4))) unsigned short;

#define C1_ 0.18033688011112042f    // (1/sqrt(64)) * log2(e)

__device__ __forceinline__ u16 f2bf(float f){
  union { float f; u32 u; } v; v.f = f;
  u32 r = v.u + 0x7FFFu + ((v.u >> 16) & 1u);
  return (u16)(r >> 16);
}
__device__ __forceinline__ u16 f2bf_fast(float f){
  union { float f; u32 u; } v; v.f = f;
  return (u16)((v.u + 0x8000u) >> 16);
}
__device__ __forceinline__ float fexp2(float x){
  float r;
  asm("v_exp_f32 %0, %1\n\ts_nop 0" : "=v"(r) : "v"(x));
  return r;
}
// async global->LDS, 16B/lane; LDS dest = wave-uniform base + lane*16
__device__ __forceinline__ void gl16(const void* g, void* l){
  __builtin_amdgcn_global_load_lds(
      (const __attribute__((address_space(1))) unsigned int*)g,
      (__attribute__((address_space(3))) unsigned int*)l, 16, 0, 0);
}

// ---------- fused prep: fp32->bf16 cvt (q,k,v) + 4x W transpose ----------
__global__ __launch_bounds__(256) void prep_k(const float* __restrict__ q,
                                              const float* __restrict__ k,
                                              const float* __restrict__ v,
                                              const float* __restrict__ W0,
                                              const float* __restrict__ W1,
                                              const float* __restrict__ W2,
                                              const float* __restrict__ W3,
                                              u16* __restrict__ dq,
                                              u16* __restrict__ dk,
                                              u16* __restrict__ dv,
                                              u16* __restrict__ WT){
  int id = blockIdx.x;
  int tid = threadIdx.x;
  if (id < 12288){
    int z = id >> 12;
    int i = (id & 4095)*256 + tid;            // n8 = 4096*256 exactly
    const float* in = (z==0)? q : (z==1)? k : v;
    u16* out = (z==0)? dq : (z==1)? dk : dv;
    const float4* p = (const float4*)(in + (size_t)i*8);
    float4 a0 = p[0], a1 = p[1];
    u16 o[8];
    o[0]=f2bf(a0.x); o[1]=f2bf(a0.y); o[2]=f2bf(a0.z); o[3]=f2bf(a0.w);
    o[4]=f2bf(a1.x); o[5]=f2bf(a1.y); o[6]=f2bf(a1.z); o[7]=f2bf(a1.w);
    *(bh8*)(out + (size_t)i*8) = *(bh8*)o;
  } else {
    int id2 = id - 12288;
    int z = id2 >> 10, b2 = id2 & 1023;
    int bx = b2 & 31, by = b2 >> 5;
    const float* in = (z==0)? W0 : (z==1)? W1 : (z==2)? W2 : W3;
    float scale = (z==0)? C1_ : 1.0f;
    u16* o = WT + (size_t)z*1024*1024;
    __shared__ u16 tile[32][33];
    int tx = tid & 31, ty = tid >> 5;         // 32 x 8
    int x0 = bx*32, y0 = by*32;
    #pragma unroll
    for (int j=0;j<32;j+=8) tile[ty+j][tx] = f2bf(in[(size_t)(y0+ty+j)*D_ + x0+tx]*scale);
    __syncthreads();
    #pragma unroll
    for (int j=0;j<32;j+=8) o[(size_t)(x0+ty+j)*D_ + y0+tx] = tile[tx][ty+j];
  }
}

// ---------- unified 8-wave GEMM: 128(M) x 256(N) tile, BK=64 ----------
// (R6-verified, unchanged)
template<int MODE>
__global__ __launch_bounds__(512) void gemm8(const u16* __restrict__ Aqk,
                                             const u16* __restrict__ Av,
                                             const u16* __restrict__ WTb,
                                             u16* __restrict__ Cqk,
                                             u16* __restrict__ VtOut,
                                             float* __restrict__ Cf){
  __shared__ __align__(16) u16 AL[2][128*64];   // 2 x 16 KB
  __shared__ __align__(16) u16 BL[2][256*64];   // 2 x 32 KB

  int hbid = blockIdx.x;
  int xcd = hbid & 7, slot = hbid >> 3;
  int pg  = xcd * (MODE==0 ? 24 : 8) + (slot >> 2);
  int x   = slot & 3;
  int y   = (MODE==0) ? (pg & 63) : pg;
  int z   = (MODE==0) ? (pg >> 6) : 0;

  const u16* A  = (MODE==0 && z==2) ? Av : (Aqk + (size_t)z*MD_);
  const u16* BT = WTb + (size_t)z*1024*1024;
  int tid = threadIdx.x;
  int w = tid >> 6, lane = tid & 63, quad = lane >> 4, ln = lane & 15;
  int wm = w >> 2, wn = w & 3;
  int rowBase = y*128, colBase = x*256;

  auto sA = [&](int buf, int kt, int c){      // c in {0,1}
    int s = c*512 + tid;
    int row = s >> 3, kc = (s & 7) ^ (row & 7);
    gl16(&A[(size_t)(rowBase + row)*D_ + kt*64 + kc*8], &AL[buf][s*8]);
  };
  auto sB = [&](int buf, int kt, int c){      // c in {0..3}
    int s = c*512 + tid;
    int row = s >> 3, kc = (s & 7) ^ (row & 7);
    gl16(&BT[(size_t)(colBase + row)*D_ + kt*64 + kc*8], &BL[buf][s*8]);
  };
  auto ridx = [&](int row, int kc){ return row*64 + ((kc ^ (row & 7))*8); };

  fx4 acc[4][4];
  #pragma unroll
  for (int i=0;i<4;i++)
    #pragma unroll
    for (int j=0;j<4;j++) acc[i][j] = (fx4){0.f,0.f,0.f,0.f};

  sA(0,0,0); sA(0,0,1); sB(0,0,0); sB(0,0,1); sB(0,0,2); sB(0,0,3);
  sB(1,1,0); sB(1,1,1); sB(1,1,2);
  asm volatile("s_waitcnt vmcnt(3)" ::: "memory");
  __builtin_amdgcn_s_barrier();

  for (int it = 0; it < 8; ++it){
    int t = 2*it;
    bool h2 = (t+2 < 16), h3 = (t+3 < 16);
    #pragma unroll
    for (int half = 0; half < 2; ++half){     // buf == half (t even)
      const u16* Ab = &AL[half][0];
      const u16* Bb = &BL[half][0];

      // ---- q0 phase ----
      bh8 bfr[4][2], af0[2][2], af1[2][2];
      #pragma unroll
      for (int n=0;n<4;n++)
        #pragma unroll
        for (int ks=0;ks<2;ks++)
          bfr[n][ks] = *(const bh8*)(&Bb[ridx(wn*64 + n*16 + ln, ks*4+quad)]);
      #pragma unroll
      for (int mi=0;mi<2;mi++)
        #pragma unroll
        for (int ks=0;ks<2;ks++)
          af0[mi][ks] = *(const bh8*)(&Ab[ridx(wm*64 + mi*16 + ln, ks*4+quad)]);
      #pragma unroll
      for (int mi=0;mi<2;mi++)
        #pragma unroll
        for (int ks=0;ks<2;ks++)
          af1[mi][ks] = *(const bh8*)(&Ab[ridx(wm*64 + 32 + mi*16 + ln, ks*4+quad)]);

      if (half == 0){
        sB(1, t+1, 3); sA(1, t+1, 0); sA(1, t+1, 1);
      } else if (h2){
        sB(0, t+2, 3); sA(0, t+2, 0); sA(0, t+2, 1);
      }
      __builtin_amdgcn_s_barrier();
      asm volatile("s_waitcnt lgkmcnt(4)" ::: "memory");   // bfr+af0 done
      __builtin_amdgcn_s_setprio(1);
      #pragma unroll
      for (int mi=0;mi<2;mi++)
        #pragma unroll
        for (int n=0;n<4;n++)
          #pragma unroll
          for (int ks=0;ks<2;ks++)
            acc[mi][n] = __builtin_amdgcn_mfma_f32_16x16x32_bf16(
                            af0[mi][ks], bfr[n][ks], acc[mi][n], 0,0,0);
      __builtin_amdgcn_s_setprio(0);
      __builtin_amdgcn_s_barrier();

      // ---- q1 phase ----
      if (half == 0){
        if (h2){ sB(0, t+2, 0); sB(0, t+2, 1); sB(0, t+2, 2); }
        if (h2) asm volatile("s_waitcnt vmcnt(3)" ::: "memory");
        else    asm volatile("s_waitcnt vmcnt(0)" ::: "memory");
      } else {
        if (h3){ sB(1, t+3, 0); sB(1, t+3, 1); sB(1, t+3, 2); }
        if (h3) asm volatile("s_waitcnt vmcnt(3)" ::: "memory");
        else    asm volatile("s_waitcnt vmcnt(0)" ::: "memory");
      }
      __builtin_amdgcn_s_barrier();
      asm volatile("s_waitcnt lgkmcnt(0)" ::: "memory");   // af1 done
      __builtin_amdgcn_s_setprio(1);
      #pragma unroll
      for (int mi=0;mi<2;mi++)
        #pragma unroll
        for (int n=0;n<4;n++)
          #pragma unroll
          for (int ks=0;ks<2;ks++)
            acc[2+mi][n] = __builtin_amdgcn_mfma_f32_16x16x32_bf16(
                              af1[mi][ks], bfr[n][ks], acc[2+mi][n], 0,0,0);
      __builtin_amdgcn_s_setprio(0);
      __builtin_amdgcn_s_barrier();
    }
  }

  #pragma unroll
  for (int m=0;m<4;m++){
    int row0 = rowBase + wm*64 + m*16 + quad*4;
    #pragma unroll
    for (int n=0;n<4;n++){
      int col = colBase + wn*64 + n*16 + ln;
      if (MODE == 1){
        #pragma unroll
        for (int r=0;r<4;r++)
          Cf[(size_t)(row0 + r)*D_ + col] = acc[m][n][r];
      } else if (z == 2){
        int bb = row0 >> 11, tok = row0 & (S_-1);
        int hh = col >> 6,  vd  = col & 63;
        us4 pk;
        #pragma unroll
        for (int r=0;r<4;r++) pk[r] = f2bf(acc[m][n][r]);
        *(us4*)&VtOut[((size_t)((bb*16+hh)*64+vd))*S_ + tok] = pk;
      } else {
        #pragma unroll
        for (int r=0;r<4;r++)
          (Cqk + (size_t)z*MD_)[(size_t)(row0 + r)*D_ + col] = f2bf(acc[m][n][r]);
      }
    }
  }
}

// ---------- flash attention, causal: uniform-makespan paired q-tiles ----------
// R10-verified base (79.1 us): paired 64-row q-tiles (j1=31-p, j2=p), 33
// K-tiles per block -> zero makespan skew; K AND V staged via
// global_load_lds (R11's V-direct regressed 2.4x: per-lane 4KB-stride V
// reads = 64 cache lines per instr). Single bundled delta vs R10: the two
// in-loop `s_waitcnt lgkmcnt(0)` hardware drains are dropped — the LDS
// pipe processes a wave's DS ops in issue order (R9 validated correctness
// of this ordering), and the post-PV drain is subsumed by __syncthreads.
// Compiler-only fences remain so TBAA (short vs ushort) cannot reorder
// the Pw write/read pairs.
__global__ __launch_bounds__(256) void attn_k(const u16* __restrict__ Q,
                                              const u16* __restrict__ Kp,
                                              const u16* __restrict__ VtG,
                                              u16* __restrict__ O){
  __shared__ __align__(16) u16 Kt[2][64*64];    // 2 x 8 KB
  __shared__ __align__(16) u16 Vt[2][64*64];    // 2 x 8 KB
  __shared__ __align__(16) u16 Pb[4*16*64];     // 8 KB

  int bh = blockIdx.x; int b = bh>>4, h = bh&15;
  int p  = blockIdx.y;                 // 0..15
  int j1 = 31 - p, j2 = p;             // paired 64-row q-tiles; (j1+1)+(j2+1)=33
  int tid = threadIdx.x;
  int w = tid >> 6, lane = tid & 63, quad = lane >> 4, ln = lane & 15;
  size_t headoff = (size_t)h*DK_;

  // per-segment state
  int q0w;                             // = qt*64 + w*16
  bh8 qf0, qf1;
  float m_i, l_i;
  fx4 oacc[4];

  auto loadQ = [&](int j){
    q0w = j*64 + w*16;
    const u16* qp = Q + (size_t)(b*S_ + q0w + ln)*D_ + headoff + quad*8;
    qf0 = *(const bh8*)qp;
    qf1 = *(const bh8*)(qp + 32);
    m_i = -3e38f; l_i = 0.f;
    #pragma unroll
    for (int r=0;r<4;r++) oacc[r] = (fx4){0.f,0.f,0.f,0.f};
  };

  auto writeO = [&](){
    float linv = 1.0f / l_i;
    float lb[4];
    #pragma unroll
    for (int r=0;r<4;r++) lb[r] = __shfl(linv, quad*4 + r, 64);
    #pragma unroll
    for (int r=0;r<4;r++)
      #pragma unroll
      for (int vt=0; vt<4; vt++){
        float ov = oacc[vt][r] * lb[r];
        O[(size_t)(b*S_ + q0w + quad*4 + r)*D_ + headoff + vt*16 + ln] = f2bf(ov);
      }
  };

  auto stage = [&](int k0, int bi){
    #pragma unroll
    for (int i=0;i<2;i++){
      int s = i*256 + tid;
      int n = s >> 3, kc = (s & 7) ^ (n & 7);
      gl16(&Kp[(size_t)(b*S_ + k0 + n)*D_ + headoff + kc*8], &Kt[bi][s*8]);
    }
    #pragma unroll
    for (int i=0;i<2;i++){
      int s = i*256 + tid;
      int vd = s >> 3, c = (s & 7) ^ (vd & 7);
      gl16(&VtG[(size_t)(bh*64 + vd)*S_ + k0 + c*8], &Vt[bi][s*8]);
    }
  };

  u16* Pw = &Pb[w*16*64];
  const int nt = 33;                   // (j1+1)+(j2+1), uniform for all blocks
  auto k0_of = [&](int i){ return (i <= j1) ? i*64 : (i - j1 - 1)*64; };

  loadQ(j1);                           // heavy segment first
  stage(0, 0);
  __syncthreads();                     // drain prologue staging

  for (int i=0; i<nt; i++){
    int cur = i & 1;
    if (i+1 < nt) stage(k0_of(i+1), cur^1);   // prefetch (spans segment boundary)
    const u16* Kc = Kt[cur];
    const u16* Vc = Vt[cur];
    int k0 = k0_of(i);
    bool diag = (i == j1) || (i == nt-1);     // last tile of each segment

    // QK^T swapped: sacc[t] = K_frag[t] x Q_frag -> S^T
    // lane (quad,ln): keys k0 + t*16 + quad*4 + r, query q0w + ln
    fx4 sacc[4];
    __builtin_amdgcn_s_setprio(1);
    #pragma unroll
    for (int t=0;t<4;t++){
      int n = t*16 + ln;
      bh8 kf0 = *(const bh8*)(&Kc[(n*8 + ( quad    ^ (ln&7)))*8]);
      bh8 kf1 = *(const bh8*)(&Kc[(n*8 + ((4+quad) ^ (ln&7)))*8]);
      fx4 zz = (fx4){0.f,0.f,0.f,0.f};
      zz = __builtin_amdgcn_mfma_f32_16x16x32_bf16(kf0, qf0, zz, 0,0,0);
      zz = __builtin_amdgcn_mfma_f32_16x16x32_bf16(kf1, qf1, zz, 0,0,0);
      sacc[t] = zz;
    }
    __builtin_amdgcn_s_setprio(0);

    int qg = q0w + ln;
    if (diag){
      #pragma unroll
      for (int t=0;t<4;t++)
        #pragma unroll
        for (int r=0;r<4;r++){
          int kg = k0 + t*16 + quad*4 + r;
          sacc[t][r] = (kg <= qg) ? sacc[t][r] : -3e38f;
        }
    }

    // row reduce: in-register tree + 2 shfl
    float tm[4];
    #pragma unroll
    for (int t=0;t<4;t++)
      tm[t] = fmaxf(fmaxf(sacc[t][0], sacc[t][1]), fmaxf(sacc[t][2], sacc[t][3]));
    float mloc = fmaxf(fmaxf(tm[0], tm[1]), fmaxf(tm[2], tm[3]));
    mloc = fmaxf(mloc, __shfl_xor(mloc, 16, 64));
    mloc = fmaxf(mloc, __shfl_xor(mloc, 32, 64));

    // defer-max: rescale only when the tile max grew past THR=8 (log2)
    if (__any(mloc > m_i + 8.0f)){
      float mn = fmaxf(m_i, mloc);
      float alpha = fexp2(m_i - mn);
      m_i = mn;
      l_i *= alpha;
      float al[4];
      #pragma unroll
      for (int r=0;r<4;r++) al[r] = __shfl(alpha, quad*4 + r, 64);
      #pragma unroll
      for (int vt=0;vt<4;vt++)
        #pragma unroll
        for (int r=0;r<4;r++)
          oacc[vt][r] *= al[r];
    }
    float mn = m_i;

    float ts[4];
    #pragma unroll
    for (int t=0;t<4;t++){
      #pragma unroll
      for (int r=0;r<4;r++) sacc[t][r] = fexp2(sacc[t][r] - mn);
      ts[t] = (sacc[t][0] + sacc[t][1]) + (sacc[t][2] + sacc[t][3]);
    }
    float rs = (ts[0] + ts[1]) + (ts[2] + ts[3]);
    rs += __shfl_xor(rs, 16, 64);
    rs += __shfl_xor(rs, 32, 64);
    l_i += rs;

    // P^T -> P: phys halfslot hs = (4t+quad) ^ (ln&14)
    #pragma unroll
    for (int t=0;t<4;t++){
      int hs = (t*4 + quad) ^ (ln & 14);
      us4 pk;
      #pragma unroll
      for (int r=0;r<4;r++) pk[r] = f2bf_fast(sacc[t][r]);
      *(us4*)&Pw[ln*64 + hs*4] = pk;
    }
    asm volatile("" ::: "memory");   // pin PW before PV (DS pipe is in-order; no HW drain)

    // PV: 64 keys in 2 chunks, vdim in 4 subtiles
    __builtin_amdgcn_s_setprio(1);
    #pragma unroll
    for (int s2=0; s2<2; s2++){
      int c = s2*4 + quad;
      int pm = c ^ ((ln>>1) & 7);
      bh8 pf = *(const bh8*)(&Pw[ln*64 + pm*8]);
      #pragma unroll
      for (int vt=0; vt<4; vt++){
        int vd = vt*16 + ln;
        bh8 vf = *(const bh8*)(&Vc[(vd*8 + (c ^ (ln&7)))*8]);
        oacc[vt] = __builtin_amdgcn_mfma_f32_16x16x32_bf16(pf, vf, oacc[vt], 0,0,0);
      }
    }
    __builtin_amdgcn_s_setprio(0);
    asm volatile("" ::: "memory");   // PV reads pinned before next-tile PW (syncthreads drains HW)

    if (i == j1){                       // segment boundary: finish j1, start j2
      writeO();
      loadQ(j2);
    }
    __syncthreads();   // prefetch arrived (vmcnt drain overlapped compute); buffers safe
  }

  writeO();                             // finish segment 2
}

extern "C" void kernel_launch(void* const* d_in, const int* in_sizes, int n_in,
                              void* d_out, int out_size, void* d_ws, size_t ws_size,
                              hipStream_t stream){
  const float* q  = (const float*)d_in[0];
  const float* k  = (const float*)d_in[1];
  const float* v  = (const float*)d_in[2];
  const float* Wq = (const float*)d_in[3];
  const float* Wk = (const float*)d_in[4];
  const float* Wv = (const float*)d_in[5];
  const float* Wo = (const float*)d_in[6];
  // d_in[7] = causal mask, statically known -> ignored

  u16* ws  = (u16*)d_ws;
  u16* WT  = ws;                                // 4 x 1M bf16 (Wq*C1, Wk, Wv, Wo)^T
  u16* xa  = WT + (size_t)4*1024*1024;          // q bf16
  u16* xb  = xa + MD_;                          // k bf16 (contiguous after xa)
  u16* Qp  = xb + MD_;                          // Q proj (C1-scaled), later O
  u16* Kp  = Qp + MD_;                          // 8 MB + 4*16 MB = 72 MB ws

  // d_out (2*MD_ u16) doubles as scratch until the final GEMM:
  u16* vb  = (u16*)d_out;                       // v bf16       [0,   MD_)
  u16* VtG = vb + MD_;                          // per-head V^T [MD_, 2*MD_)

  prep_k<<<dim3(16384), 256, 0, stream>>>(q, k, v, Wq, Wk, Wv, Wo, xa, xb, vb, WT);

  gemm8<0><<<dim3(768), 512, 0, stream>>>(xa, vb, WT, Qp, VtG, nullptr);      // Qp, Kp, VtG

  attn_k<<<dim3(B_*H_, 16), 256, 0, stream>>>(Qp, Kp, VtG, Qp);               // O over Q

  gemm8<1><<<dim3(256), 512, 0, stream>>>(Qp, nullptr, WT + (size_t)3*1024*1024,
                                          nullptr, nullptr, (float*)d_out);
}